// Round 1
// baseline (269.498 us; speedup 1.0000x reference)
//
#include <hip/hip_runtime.h>
#include <hip/hip_bf16.h>

// Fused MHA: x->(Q,K,V) proj (bf16 hi/lo split MFMA) -> flash attention
// (exp(s)-1 trick for precision) -> output proj (split MFMA).
// B=2 S=2048 D_IN=1024 H=16 DH=64.

typedef unsigned short u16;
typedef __attribute__((ext_vector_type(8))) short bf16x8;
typedef __attribute__((ext_vector_type(4))) float f32x4;
typedef __attribute__((ext_vector_type(4))) unsigned short u16x4;

#define SCALE 1.52587890625e-05f  // 1/(64*64*16)

__device__ __forceinline__ u16 f2bf(float f) {
  unsigned int u = __float_as_uint(f);
  return (u16)((u + 0x7FFFu + ((u >> 16) & 1u)) >> 16);  // RNE
}
__device__ __forceinline__ float bf2f(u16 v) {
  return __uint_as_float(((unsigned int)v) << 16);
}

__device__ __forceinline__ f32x4 mfma16(bf16x8 a, bf16x8 b, f32x4 c) {
  return __builtin_amdgcn_mfma_f32_16x16x32_bf16(a, b, c, 0, 0, 0);
}

// async global->LDS, 16B per lane; lds base must be wave-uniform (HW adds lane*16)
__device__ __forceinline__ void gl_lds16(const u16* g, u16* l) {
  __builtin_amdgcn_global_load_lds((const __attribute__((address_space(1))) void*)g,
                                   (__attribute__((address_space(3))) void*)l, 16, 0, 0);
}

// ---------------- split fp32 -> bf16 hi + bf16 lo ----------------
__global__ void split_f32(const float* __restrict__ x, u16* __restrict__ hi,
                          u16* __restrict__ lo, int n4) {
  int i = blockIdx.x * 256 + threadIdx.x;
  if (i >= n4) return;
  float4 v = ((const float4*)x)[i];
  float vv[4] = {v.x, v.y, v.z, v.w};
  u16x4 h, l;
#pragma unroll
  for (int j = 0; j < 4; ++j) {
    u16 hb = f2bf(vv[j]);
    h[j] = hb;
    l[j] = f2bf(vv[j] - bf2f(hb));
  }
  ((u16x4*)hi)[i] = h;
  ((u16x4*)lo)[i] = l;
}

// ---- kernel[t][h][m][d] (fp32) -> Wt[n=(t*16+h)*64+d][k=m] bf16 hi/lo ----
__global__ void prep_w(const float* __restrict__ w, u16* __restrict__ bhi,
                       u16* __restrict__ blo) {
  __shared__ float t[64 * 65];
  int mt = blockIdx.x, th = blockIdx.y;
  int tid = threadIdx.x;
  for (int i = 0; i < 16; ++i) {
    int idx = tid + i * 256;
    int ms = idx >> 6, d = idx & 63;
    t[d * 65 + ms] = w[(size_t)(th * 1024 + mt * 64 + ms) * 64 + d];
  }
  __syncthreads();
  for (int i = 0; i < 16; ++i) {
    int idx = tid + i * 256;
    int ds = idx >> 6, mm = idx & 63;
    float v = t[ds * 65 + mm];
    size_t o = (size_t)(th * 64 + ds) * 1024 + mt * 64 + mm;
    u16 hb = f2bf(v);
    bhi[o] = hb;
    blo[o] = f2bf(v - bf2f(hb));
  }
}

// ---- WO[f][m] fp32 -> WOt[n=m][k'=h*64+d] where f=d*16+h ----
// (absorbs the (B,S,d,H)->flat permutation into the weight layout)
__global__ void prep_wo(const float* __restrict__ wo, u16* __restrict__ bhi,
                        u16* __restrict__ blo) {
  __shared__ float t[64 * 65];
  int mt = blockIdx.x, kt = blockIdx.y;  // kt = h
  int tid = threadIdx.x;
  for (int i = 0; i < 16; ++i) {
    int idx = tid + i * 256;
    int d = idx >> 6, mm = idx & 63;
    t[mm * 65 + d] = wo[(size_t)(d * 16 + kt) * 1024 + mt * 64 + mm];
  }
  __syncthreads();
  for (int i = 0; i < 16; ++i) {
    int idx = tid + i * 256;
    int mr = idx >> 6, dc = idx & 63;
    float v = t[mr * 65 + dc];
    size_t o = (size_t)(mt * 64 + mr) * 1024 + kt * 64 + dc;
    u16 hb = f2bf(v);
    bhi[o] = hb;
    blo[o] = f2bf(v - bf2f(hb));
  }
}

// ---------------- split-compensated bf16 GEMM ----------------
// C[m][n] = sum_k A[m][k]*B[n][k], A=Ah+Al, B=Bh+Bl, 3-term MFMA.
// MODE 0: scatter to Q/K/V (B,H,S,DH) bf16.  MODE 1: fp32 C out.
template <int MODE>
__global__ __launch_bounds__(256, 2) void gemm_split(
    const u16* __restrict__ Ah_g, const u16* __restrict__ Al_g,
    const u16* __restrict__ Bh_g, const u16* __restrict__ Bl_g,
    u16* __restrict__ Qb, u16* __restrict__ Kb, u16* __restrict__ Vb,
    float* __restrict__ Cf) {
  __shared__ __align__(16) u16 Ah[128 * 32];
  __shared__ __align__(16) u16 Al[128 * 32];
  __shared__ __align__(16) u16 Bh[128 * 32];
  __shared__ __align__(16) u16 Bl[128 * 32];
  int tid = threadIdx.x;
  int lane = tid & 63;
  int l15 = lane & 15, g = lane >> 4;
  int wv = tid >> 6, wm = wv >> 1, wn = wv & 1;
  int m0 = blockIdx.x * 128, n0 = blockIdx.y * 128;

  f32x4 acc[4][4];
#pragma unroll
  for (int i = 0; i < 4; ++i)
#pragma unroll
    for (int j = 0; j < 4; ++j) acc[i][j] = (f32x4){0.f, 0.f, 0.f, 0.f};

  int c0 = tid, c1 = tid + 256;
  int r0 = c0 >> 2, o0 = (c0 & 3) * 8;
  int r1 = c1 >> 2, o1 = (c1 & 3) * 8;
  int wb0 = (tid & 192) * 8, wb1 = ((tid & 192) + 256) * 8;  // elem offsets

  for (int kk = 0; kk < 32; ++kk) {
    int k0 = kk * 32;
    __syncthreads();
    gl_lds16(Ah_g + (size_t)(m0 + r0) * 1024 + k0 + o0, &Ah[wb0]);
    gl_lds16(Ah_g + (size_t)(m0 + r1) * 1024 + k0 + o1, &Ah[wb1]);
    gl_lds16(Al_g + (size_t)(m0 + r0) * 1024 + k0 + o0, &Al[wb0]);
    gl_lds16(Al_g + (size_t)(m0 + r1) * 1024 + k0 + o1, &Al[wb1]);
    gl_lds16(Bh_g + (size_t)(n0 + r0) * 1024 + k0 + o0, &Bh[wb0]);
    gl_lds16(Bh_g + (size_t)(n0 + r1) * 1024 + k0 + o1, &Bh[wb1]);
    gl_lds16(Bl_g + (size_t)(n0 + r0) * 1024 + k0 + o0, &Bl[wb0]);
    gl_lds16(Bl_g + (size_t)(n0 + r1) * 1024 + k0 + o1, &Bl[wb1]);
    __syncthreads();

    bf16x8 fa_h[4], fa_l[4], fb_h[4], fb_l[4];
#pragma unroll
    for (int mi = 0; mi < 4; ++mi) {
      int off = (wm * 64 + mi * 16 + l15) * 64 + g * 16;  // bytes
      fa_h[mi] = *(const bf16x8*)((const char*)Ah + off);
      fa_l[mi] = *(const bf16x8*)((const char*)Al + off);
    }
#pragma unroll
    for (int ni = 0; ni < 4; ++ni) {
      int off = (wn * 64 + ni * 16 + l15) * 64 + g * 16;
      fb_h[ni] = *(const bf16x8*)((const char*)Bh + off);
      fb_l[ni] = *(const bf16x8*)((const char*)Bl + off);
    }
#pragma unroll
    for (int mi = 0; mi < 4; ++mi)
#pragma unroll
      for (int ni = 0; ni < 4; ++ni) {
        acc[mi][ni] = mfma16(fa_h[mi], fb_h[ni], acc[mi][ni]);
        acc[mi][ni] = mfma16(fa_h[mi], fb_l[ni], acc[mi][ni]);
        acc[mi][ni] = mfma16(fa_l[mi], fb_h[ni], acc[mi][ni]);
      }
  }

#pragma unroll
  for (int mi = 0; mi < 4; ++mi)
#pragma unroll
    for (int ni = 0; ni < 4; ++ni)
#pragma unroll
      for (int r = 0; r < 4; ++r) {
        int m = m0 + wm * 64 + mi * 16 + g * 4 + r;
        int n = n0 + wn * 64 + ni * 16 + l15;
        float v = acc[mi][ni][r];
        if (MODE == 0) {
          int th = n >> 6, d = n & 63;
          int t = th >> 4, h = th & 15;
          int b = m >> 11, s = m & 2047;
          u16* o = (t == 0) ? Qb : (t == 1) ? Kb : Vb;
          o[(size_t)((b * 16 + h) * 2048 + s) * 64 + d] = f2bf(v);
        } else {
          Cf[(size_t)m * 1024 + n] = v;
        }
      }
}

// ---------------- flash attention ----------------
// Swapped QK^T (mfma(K,Q) -> D[t][q], q=lane&15) so P stays in registers as
// PV's A-operand. P = 1 + e, e = exp(s*SCALE)-1 kept in bf16 at full precision;
// numerator = colsum(V) (ones MFMA) + sum e*V; denom = 2048 + sum e.
__global__ __launch_bounds__(256, 2) void attn(
    const u16* __restrict__ Qb, const u16* __restrict__ Kb,
    const u16* __restrict__ Vb, u16* __restrict__ AOhi,
    u16* __restrict__ AOlo) {
  __shared__ __align__(16) u16 Kl[128 * 64];
  __shared__ __align__(16) u16 Vl[128 * 64];
  int qt = blockIdx.x, bh = blockIdx.y;
  int tid = threadIdx.x, lane = tid & 63, w = tid >> 6;
  int l15 = lane & 15, g = lane >> 4;
  size_t hb = (size_t)bh * 2048 * 64;
  const u16* Qg = Qb + hb;
  const u16* Kg = Kb + hb;
  const u16* Vg = Vb + hb;
  int q_base = qt * 128 + w * 32;

  bf16x8 qf[2][2];
#pragma unroll
  for (int q2 = 0; q2 < 2; ++q2)
#pragma unroll
    for (int ds = 0; ds < 2; ++ds)
      qf[q2][ds] = *(const bf16x8*)(Qg + (size_t)(q_base + q2 * 16 + l15) * 64 +
                                    ds * 32 + g * 8);

  f32x4 acc_e[2][4], acc_c[4];
#pragma unroll
  for (int i = 0; i < 4; ++i) {
    acc_c[i] = (f32x4){0.f, 0.f, 0.f, 0.f};
    acc_e[0][i] = (f32x4){0.f, 0.f, 0.f, 0.f};
    acc_e[1][i] = (f32x4){0.f, 0.f, 0.f, 0.f};
  }
  float lsum[2] = {0.f, 0.f};
  bf16x8 ones;
#pragma unroll
  for (int j = 0; j < 8; ++j) ones[j] = (short)0x3F80;  // bf16 1.0

  int wbase = w * 64;  // staging chunk base per wave

  for (int tt0 = 0; tt0 < 16; ++tt0) {
    int t0 = tt0 * 128;
    __syncthreads();
    // stage K,V with XOR-swizzle folded into the GLOBAL source (m173 pattern)
#pragma unroll
    for (int i = 0; i < 4; ++i) {
      int c = tid + i * 256;
      int row = c >> 3, blk = c & 7;
      size_t so = (size_t)(t0 + row) * 64 + ((blk ^ (row & 7)) * 8);
      gl_lds16(Kg + so, &Kl[(wbase + i * 256) * 8]);
      gl_lds16(Vg + so, &Vl[(wbase + i * 256) * 8]);
    }
    __syncthreads();

    // QK^T: sc[q2][tt] = D[t][q] for t-16-tile tt
    f32x4 sc[2][8];
#pragma unroll
    for (int tt = 0; tt < 8; ++tt) {
      sc[0][tt] = (f32x4){0.f, 0.f, 0.f, 0.f};
      sc[1][tt] = (f32x4){0.f, 0.f, 0.f, 0.f};
    }
#pragma unroll
    for (int tt = 0; tt < 8; ++tt)
#pragma unroll
      for (int ds = 0; ds < 2; ++ds) {
        int row = tt * 16 + l15;
        int off = row * 128 + ((((ds * 4 + g) ^ (row & 7)) << 4));
        bf16x8 kf = *(const bf16x8*)((const char*)Kl + off);
        sc[0][tt] = mfma16(kf, qf[0][ds], sc[0][tt]);
        sc[1][tt] = mfma16(kf, qf[1][ds], sc[1][tt]);
      }

    // e = exp(s)-1; pack into PV A-frags (kappa(g,blk*4+r) = 16blk+4g+r)
    bf16x8 pe[2][4];
#pragma unroll
    for (int q2 = 0; q2 < 2; ++q2)
#pragma unroll
      for (int ks = 0; ks < 4; ++ks)
#pragma unroll
        for (int blk = 0; blk < 2; ++blk)
#pragma unroll
          for (int r = 0; r < 4; ++r) {
            float e = __expf(sc[q2][ks * 2 + blk][r] * SCALE) - 1.0f;
            lsum[q2] += e;
            pe[q2][ks][blk * 4 + r] = (short)f2bf(e);
          }

    // PV: acc_c += ones*V (colsum), acc_e += e*V
#pragma unroll
    for (int ks = 0; ks < 4; ++ks)
#pragma unroll
      for (int dt = 0; dt < 4; ++dt) {
        bf16x8 vf;
#pragma unroll
        for (int sl = 0; sl < 8; ++sl) {
          int blk = sl >> 2, r = sl & 3;
          int t = ks * 32 + blk * 16 + g * 4 + r;
          int col = dt * 16 + l15;
          int off = t * 128 + ((col * 2) ^ ((t & 7) << 4));
          vf[sl] = *(const short*)((const char*)Vl + off);
        }
        acc_c[dt] = mfma16(ones, vf, acc_c[dt]);
        acc_e[0][dt] = mfma16(pe[0][ks], vf, acc_e[0][dt]);
        acc_e[1][dt] = mfma16(pe[1][ks], vf, acc_e[1][dt]);
      }
  }

  float lt[2];
#pragma unroll
  for (int q2 = 0; q2 < 2; ++q2) {
    float v = lsum[q2];
    v += __shfl_xor(v, 16);
    v += __shfl_xor(v, 32);
    lt[q2] = 2048.0f + v;
  }
  float linv[2][4];
#pragma unroll
  for (int q2 = 0; q2 < 2; ++q2)
#pragma unroll
    for (int r = 0; r < 4; ++r) linv[q2][r] = 1.0f / __shfl(lt[q2], g * 4 + r);

  int b = bh >> 4, h = bh & 15;
#pragma unroll
  for (int q2 = 0; q2 < 2; ++q2)
#pragma unroll
    for (int dt = 0; dt < 4; ++dt)
#pragma unroll
      for (int r = 0; r < 4; ++r) {
        int s = q_base + q2 * 16 + g * 4 + r;
        int d = dt * 16 + l15;
        float o = (acc_c[dt][r] + acc_e[q2][dt][r]) * linv[q2][r];
        u16 hv = f2bf(o);
        size_t ao = ((size_t)(b * 2048 + s) * 16 + h) * 64 + d;  // [b][s][h*64+d]
        AOhi[ao] = hv;
        AOlo[ao] = f2bf(o - bf2f(hv));
      }
}

extern "C" void kernel_launch(void* const* d_in, const int* in_sizes, int n_in,
                              void* d_out, int out_size, void* d_ws,
                              size_t ws_size, hipStream_t stream) {
  const float* x = (const float*)d_in[0];    // (2,2048,1024)
  const float* krn = (const float*)d_in[1];  // (3,16,1024,64)
  const float* wo = (const float*)d_in[2];   // (1,1024,1024)
  float* out = (float*)d_out;

  u16* p = (u16*)d_ws;  // total ~75.5 MB
  u16* Xhi = p;   p += 4096 * 1024;
  u16* Xlo = p;   p += 4096 * 1024;
  u16* Wthi = p;  p += 3072 * 1024;
  u16* Wtlo = p;  p += 3072 * 1024;
  u16* WOthi = p; p += 1024 * 1024;
  u16* WOtlo = p; p += 1024 * 1024;
  u16* Qb = p;    p += 4194304;
  u16* Kb = p;    p += 4194304;
  u16* Vb = p;    p += 4194304;
  u16* AOhi = p;  p += 4194304;
  u16* AOlo = p;  p += 4194304;

  split_f32<<<4096, 256, 0, stream>>>(x, Xhi, Xlo, 1048576);
  prep_w<<<dim3(16, 48), 256, 0, stream>>>(krn, Wthi, Wtlo);
  prep_wo<<<dim3(16, 16), 256, 0, stream>>>(wo, WOthi, WOtlo);
  gemm_split<0><<<dim3(32, 24), 256, 0, stream>>>(Xhi, Xlo, Wthi, Wtlo, Qb, Kb,
                                                  Vb, nullptr);
  attn<<<dim3(16, 32), 256, 0, stream>>>(Qb, Kb, Vb, AOhi, AOlo);
  gemm_split<1><<<dim3(32, 8), 256, 0, stream>>>(AOhi, AOlo, WOthi, WOtlo,
                                                 nullptr, nullptr, nullptr, out);
}

// Round 2
// 259.749 us; speedup vs baseline: 1.0375x; 1.0375x over previous
//
#include <hip/hip_runtime.h>
#include <hip/hip_bf16.h>

// Fused MHA: x->(Q,K,V) proj (bf16 hi/lo split MFMA) -> flash attention
// (exp(s)-1 trick, V transposed, 2-phase pipelined) -> output proj.
// B=2 S=2048 D_IN=1024 H=16 DH=64.

typedef unsigned short u16;
typedef __attribute__((ext_vector_type(8))) short bf16x8;
typedef __attribute__((ext_vector_type(4))) short bf16x4;
typedef __attribute__((ext_vector_type(4))) float f32x4;
typedef __attribute__((ext_vector_type(4))) unsigned short u16x4;
typedef __attribute__((ext_vector_type(8))) unsigned short u16x8;

#define SCALE 1.52587890625e-05f  // 1/(64*64*16), folded into Q weights

__device__ __forceinline__ u16 f2bf(float f) {
  unsigned int u = __float_as_uint(f);
  return (u16)((u + 0x7FFFu + ((u >> 16) & 1u)) >> 16);  // RNE
}
__device__ __forceinline__ float bf2f(u16 v) {
  return __uint_as_float(((unsigned int)v) << 16);
}

__device__ __forceinline__ f32x4 mfma16(bf16x8 a, bf16x8 b, f32x4 c) {
  return __builtin_amdgcn_mfma_f32_16x16x32_bf16(a, b, c, 0, 0, 0);
}

// async global->LDS, 16B/lane; LDS base wave-uniform (HW adds lane*16)
__device__ __forceinline__ void gl_lds16(const u16* g, u16* l) {
  __builtin_amdgcn_global_load_lds((const __attribute__((address_space(1))) void*)g,
                                   (__attribute__((address_space(3))) void*)l, 16, 0, 0);
}

// ---------------- split fp32 -> bf16 hi + bf16 lo ----------------
__global__ void split_f32(const float* __restrict__ x, u16* __restrict__ hi,
                          u16* __restrict__ lo, int n4) {
  int i = blockIdx.x * 256 + threadIdx.x;
  if (i >= n4) return;
  float4 v = ((const float4*)x)[i];
  float vv[4] = {v.x, v.y, v.z, v.w};
  u16x4 h, l;
#pragma unroll
  for (int j = 0; j < 4; ++j) {
    u16 hb = f2bf(vv[j]);
    h[j] = hb;
    l[j] = f2bf(vv[j] - bf2f(hb));
  }
  ((u16x4*)hi)[i] = h;
  ((u16x4*)lo)[i] = l;
}

// ---- kernel[t][h][m][d] (fp32) -> Wt[n=(t*16+h)*64+d][k=m] bf16 hi/lo ----
// SCALE folded into Q weights (t==0) so attn skips the per-score multiply.
__global__ void prep_w(const float* __restrict__ w, u16* __restrict__ bhi,
                       u16* __restrict__ blo) {
  __shared__ float t[64 * 65];
  int mt = blockIdx.x, th = blockIdx.y;
  float scl = (th < 16) ? SCALE : 1.0f;
  int tid = threadIdx.x;
  for (int i = 0; i < 16; ++i) {
    int idx = tid + i * 256;
    int ms = idx >> 6, d = idx & 63;
    t[d * 65 + ms] = w[(size_t)(th * 1024 + mt * 64 + ms) * 64 + d];
  }
  __syncthreads();
  for (int i = 0; i < 16; ++i) {
    int idx = tid + i * 256;
    int ds = idx >> 6, mm = idx & 63;
    float v = t[ds * 65 + mm] * scl;
    size_t o = (size_t)(th * 64 + ds) * 1024 + mt * 64 + mm;
    u16 hb = f2bf(v);
    bhi[o] = hb;
    blo[o] = f2bf(v - bf2f(hb));
  }
}

// ---- WO[f][m] fp32 -> WOt[n=m][k'=h*64+d] where f=d*16+h ----
__global__ void prep_wo(const float* __restrict__ wo, u16* __restrict__ bhi,
                        u16* __restrict__ blo) {
  __shared__ float t[64 * 65];
  int mt = blockIdx.x, kt = blockIdx.y;  // kt = h
  int tid = threadIdx.x;
  for (int i = 0; i < 16; ++i) {
    int idx = tid + i * 256;
    int d = idx >> 6, mm = idx & 63;
    t[mm * 65 + d] = wo[(size_t)(d * 16 + kt) * 1024 + mt * 64 + mm];
  }
  __syncthreads();
  for (int i = 0; i < 16; ++i) {
    int idx = tid + i * 256;
    int mr = idx >> 6, dc = idx & 63;
    float v = t[mr * 65 + dc];
    size_t o = (size_t)(mt * 64 + mr) * 1024 + kt * 64 + dc;
    u16 hb = f2bf(v);
    bhi[o] = hb;
    blo[o] = f2bf(v - bf2f(hb));
  }
}

// ---------------- split-compensated bf16 GEMM ----------------
// MODE 0: scatter to Q[bh][s][d], K[bh][s][d], V TRANSPOSED Vt[bh][d][s].
// MODE 1: fp32 C out.
template <int MODE>
__global__ __launch_bounds__(256, 2) void gemm_split(
    const u16* __restrict__ Ah_g, const u16* __restrict__ Al_g,
    const u16* __restrict__ Bh_g, const u16* __restrict__ Bl_g,
    u16* __restrict__ Qb, u16* __restrict__ Kb, u16* __restrict__ Vb,
    float* __restrict__ Cf) {
  __shared__ __align__(16) u16 Ah[128 * 32];
  __shared__ __align__(16) u16 Al[128 * 32];
  __shared__ __align__(16) u16 Bh[128 * 32];
  __shared__ __align__(16) u16 Bl[128 * 32];
  int tid = threadIdx.x;
  int lane = tid & 63;
  int l15 = lane & 15, g = lane >> 4;
  int wv = tid >> 6, wm = wv >> 1, wn = wv & 1;
  int m0 = blockIdx.x * 128, n0 = blockIdx.y * 128;

  f32x4 acc[4][4];
#pragma unroll
  for (int i = 0; i < 4; ++i)
#pragma unroll
    for (int j = 0; j < 4; ++j) acc[i][j] = (f32x4){0.f, 0.f, 0.f, 0.f};

  int c0 = tid, c1 = tid + 256;
  int r0 = c0 >> 2, o0 = (c0 & 3) * 8;
  int r1 = c1 >> 2, o1 = (c1 & 3) * 8;
  int wb0 = (tid & 192) * 8, wb1 = ((tid & 192) + 256) * 8;

  for (int kk = 0; kk < 32; ++kk) {
    int k0 = kk * 32;
    __syncthreads();
    gl_lds16(Ah_g + (size_t)(m0 + r0) * 1024 + k0 + o0, &Ah[wb0]);
    gl_lds16(Ah_g + (size_t)(m0 + r1) * 1024 + k0 + o1, &Ah[wb1]);
    gl_lds16(Al_g + (size_t)(m0 + r0) * 1024 + k0 + o0, &Al[wb0]);
    gl_lds16(Al_g + (size_t)(m0 + r1) * 1024 + k0 + o1, &Al[wb1]);
    gl_lds16(Bh_g + (size_t)(n0 + r0) * 1024 + k0 + o0, &Bh[wb0]);
    gl_lds16(Bh_g + (size_t)(n0 + r1) * 1024 + k0 + o1, &Bh[wb1]);
    gl_lds16(Bl_g + (size_t)(n0 + r0) * 1024 + k0 + o0, &Bl[wb0]);
    gl_lds16(Bl_g + (size_t)(n0 + r1) * 1024 + k0 + o1, &Bl[wb1]);
    __syncthreads();

    bf16x8 fa_h[4], fa_l[4], fb_h[4], fb_l[4];
#pragma unroll
    for (int mi = 0; mi < 4; ++mi) {
      int off = (wm * 64 + mi * 16 + l15) * 64 + g * 16;  // bytes
      fa_h[mi] = *(const bf16x8*)((const char*)Ah + off);
      fa_l[mi] = *(const bf16x8*)((const char*)Al + off);
    }
#pragma unroll
    for (int ni = 0; ni < 4; ++ni) {
      int off = (wn * 64 + ni * 16 + l15) * 64 + g * 16;
      fb_h[ni] = *(const bf16x8*)((const char*)Bh + off);
      fb_l[ni] = *(const bf16x8*)((const char*)Bl + off);
    }
#pragma unroll
    for (int mi = 0; mi < 4; ++mi)
#pragma unroll
      for (int ni = 0; ni < 4; ++ni) {
        acc[mi][ni] = mfma16(fa_h[mi], fb_h[ni], acc[mi][ni]);
        acc[mi][ni] = mfma16(fa_h[mi], fb_l[ni], acc[mi][ni]);
        acc[mi][ni] = mfma16(fa_l[mi], fb_h[ni], acc[mi][ni]);
      }
  }

#pragma unroll
  for (int mi = 0; mi < 4; ++mi)
#pragma unroll
    for (int ni = 0; ni < 4; ++ni)
#pragma unroll
      for (int r = 0; r < 4; ++r) {
        int m = m0 + wm * 64 + mi * 16 + g * 4 + r;
        int n = n0 + wn * 64 + ni * 16 + l15;
        float v = acc[mi][ni][r];
        if (MODE == 0) {
          int th = n >> 6, d = n & 63;
          int t = th >> 4, h = th & 15;
          int b = m >> 11, s = m & 2047;
          if (t == 0)
            Qb[(size_t)((b * 16 + h) * 2048 + s) * 64 + d] = f2bf(v);
          else if (t == 1)
            Kb[(size_t)((b * 16 + h) * 2048 + s) * 64 + d] = f2bf(v);
          else
            Vb[(size_t)((b * 16 + h) * 64 + d) * 2048 + s] = f2bf(v);  // V^T
        } else {
          Cf[(size_t)m * 1024 + n] = v;
        }
      }
}

// ---- colsum over t of bf16 V (from Vt[bh][d][s]) -> cs[bh*64+d] fp32 ----
__global__ void colsum_v(const u16* __restrict__ Vt, float* __restrict__ cs) {
  int bh = blockIdx.x, tid = threadIdx.x;
  int d = tid >> 2, q = tid & 3;
  const u16x8* row = (const u16x8*)(Vt + (size_t)(bh * 64 + d) * 2048 + q * 512);
  float s = 0.f;
  for (int i = 0; i < 64; ++i) {
    u16x8 v = row[i];
#pragma unroll
    for (int j = 0; j < 8; ++j) s += bf2f(v[j]);
  }
  s += __shfl_xor(s, 1);
  s += __shfl_xor(s, 2);
  if (q == 0) cs[bh * 64 + d] = s;
}

// ---------------- flash attention ----------------
// Swapped QK^T (mfma(K,Q) -> D[t][q], q=lane&15); P = 1 + e where
// e = exp(s)-1 in bf16 (full precision near 0); numerator = csum + sum e*V;
// denom = 2048 + sum e. V^T in LDS with (d&7)<<4 XOR swizzle so V-fragments
// are 2x ds_read_b64 (PV k-slot permutation matches pe packing).
// 2-phase double-buffered staging: issue next tile's gl_lds before compute.
__global__ __launch_bounds__(256, 2) void attn(
    const u16* __restrict__ Qb, const u16* __restrict__ Kb,
    const u16* __restrict__ Vt, const float* __restrict__ csum,
    u16* __restrict__ AOhi, u16* __restrict__ AOlo) {
  __shared__ __align__(16) u16 Kl[2][128 * 64];
  __shared__ __align__(16) u16 Vl[2][64 * 128];
  // XCD-bijective swizzle: 512 wgs, 8 XCDs -> each XCD owns 4 heads' K/V
  int swz = (blockIdx.x & 7) * 64 + (blockIdx.x >> 3);
  int qt = swz & 15, bh = swz >> 4;
  int tid = threadIdx.x, lane = tid & 63, w = tid >> 6;
  int l15 = lane & 15, g = lane >> 4;
  const u16* Qg = Qb + (size_t)bh * 2048 * 64;
  const u16* Kg = Kb + (size_t)bh * 2048 * 64;
  const u16* Vg = Vt + (size_t)bh * 64 * 2048;
  int q_base = qt * 128 + w * 32;
  int wbase = tid & 192;  // w*64, chunk base per wave

  bf16x8 qf[2][2];
#pragma unroll
  for (int q2 = 0; q2 < 2; ++q2)
#pragma unroll
    for (int ds = 0; ds < 2; ++ds)
      qf[q2][ds] = *(const bf16x8*)(Qg + (size_t)(q_base + q2 * 16 + l15) * 64 +
                                    ds * 32 + g * 8);

  f32x4 acc_e[2][4];
#pragma unroll
  for (int i = 0; i < 4; ++i) {
    acc_e[0][i] = (f32x4){0.f, 0.f, 0.f, 0.f};
    acc_e[1][i] = (f32x4){0.f, 0.f, 0.f, 0.f};
  }
  float lsum[2] = {0.f, 0.f};

  auto STAGE = [&](int buf, int tt0) {
    int t0 = tt0 * 128;
#pragma unroll
    for (int i = 0; i < 4; ++i) {
      int c = tid + i * 256;
      int krow = c >> 3, kblk = c & 7;
      gl_lds16(Kg + (size_t)(t0 + krow) * 64 + ((kblk ^ (krow & 7)) * 8),
               &Kl[buf][(wbase + i * 256) * 8]);
      int vd = c >> 4, vsb = c & 15;
      gl_lds16(Vg + (size_t)vd * 2048 + t0 + ((vsb ^ (vd & 7)) * 8),
               &Vl[buf][(wbase + i * 256) * 8]);
    }
  };

  STAGE(0, 0);

  for (int tt0 = 0; tt0 < 16; ++tt0) {
    int cur = tt0 & 1;
    // barrier: own vmcnt drained (buf[cur] staged) + all waves done with buf[cur^1]
    __syncthreads();
    if (tt0 + 1 < 16) STAGE(cur ^ 1, tt0 + 1);

    const char* Kc = (const char*)&Kl[cur][0];
    const char* Vc = (const char*)&Vl[cur][0];

    // QK^T: sc[q2][tt] = D[t][q]
    f32x4 sc[2][8];
#pragma unroll
    for (int tt = 0; tt < 8; ++tt) {
      sc[0][tt] = (f32x4){0.f, 0.f, 0.f, 0.f};
      sc[1][tt] = (f32x4){0.f, 0.f, 0.f, 0.f};
    }
#pragma unroll
    for (int tt = 0; tt < 8; ++tt)
#pragma unroll
      for (int ds = 0; ds < 2; ++ds) {
        int row = tt * 16 + l15;
        int off = row * 128 + ((((ds * 4 + g) ^ (row & 7)) << 4));
        bf16x8 kf = *(const bf16x8*)(Kc + off);
        sc[0][tt] = mfma16(kf, qf[0][ds], sc[0][tt]);
        sc[1][tt] = mfma16(kf, qf[1][ds], sc[1][tt]);
      }

    // e = exp(s)-1; truncating bf16 pack (error ~2^-9 relative of e, negligible)
    bf16x8 pe[2][4];
#pragma unroll
    for (int q2 = 0; q2 < 2; ++q2)
#pragma unroll
      for (int ks = 0; ks < 4; ++ks)
#pragma unroll
        for (int blk = 0; blk < 2; ++blk)
#pragma unroll
          for (int r = 0; r < 4; ++r) {
            float e = __expf(sc[q2][ks * 2 + blk][r]) - 1.0f;
            lsum[q2] += e;
            pe[q2][ks][blk * 4 + r] = (short)(__float_as_uint(e) >> 16);
          }

    // PV: acc_e += e*V via V^T rows; fragment = 2x ds_read_b64
    int xm = (l15 & 7) << 4;
    const char* Vrow = Vc + l15 * 256;
#pragma unroll
    for (int ks = 0; ks < 4; ++ks) {
      int t0a = (ks * 64 + 8 * g) ^ xm;
      int t1a = (ks * 64 + 32 + 8 * g) ^ xm;
#pragma unroll
      for (int dt = 0; dt < 4; ++dt) {
        bf16x4 lo = *(const bf16x4*)(Vrow + dt * 4096 + t0a);
        bf16x4 hi = *(const bf16x4*)(Vrow + dt * 4096 + t1a);
        bf16x8 vf = (bf16x8){lo[0], lo[1], lo[2], lo[3],
                             hi[0], hi[1], hi[2], hi[3]};
        acc_e[0][dt] = mfma16(pe[0][ks], vf, acc_e[0][dt]);
        acc_e[1][dt] = mfma16(pe[1][ks], vf, acc_e[1][dt]);
      }
    }
  }

  float lt[2];
#pragma unroll
  for (int q2 = 0; q2 < 2; ++q2) {
    float v = lsum[q2];
    v += __shfl_xor(v, 16);
    v += __shfl_xor(v, 32);
    lt[q2] = 2048.0f + v;
  }
  float linv[2][4];
#pragma unroll
  for (int q2 = 0; q2 < 2; ++q2)
#pragma unroll
    for (int r = 0; r < 4; ++r) linv[q2][r] = 1.0f / __shfl(lt[q2], g * 4 + r);

  int b = bh >> 4, h = bh & 15;
#pragma unroll
  for (int q2 = 0; q2 < 2; ++q2)
#pragma unroll
    for (int dt = 0; dt < 4; ++dt) {
      float cv = csum[bh * 64 + dt * 16 + l15];
#pragma unroll
      for (int r = 0; r < 4; ++r) {
        int s = q_base + q2 * 16 + g * 4 + r;
        int d = dt * 16 + l15;
        float o = (cv + acc_e[q2][dt][r]) * linv[q2][r];
        u16 hv = f2bf(o);
        size_t ao = ((size_t)(b * 2048 + s) * 16 + h) * 64 + d;
        AOhi[ao] = hv;
        AOlo[ao] = f2bf(o - bf2f(hv));
      }
    }
}

extern "C" void kernel_launch(void* const* d_in, const int* in_sizes, int n_in,
                              void* d_out, int out_size, void* d_ws,
                              size_t ws_size, hipStream_t stream) {
  const float* x = (const float*)d_in[0];    // (2,2048,1024)
  const float* krn = (const float*)d_in[1];  // (3,16,1024,64)
  const float* wo = (const float*)d_in[2];   // (1,1024,1024)
  float* out = (float*)d_out;

  u16* p = (u16*)d_ws;  // total ~75.6 MB
  u16* Xhi = p;   p += 4096 * 1024;
  u16* Xlo = p;   p += 4096 * 1024;
  u16* Wthi = p;  p += 3072 * 1024;
  u16* Wtlo = p;  p += 3072 * 1024;
  u16* WOthi = p; p += 1024 * 1024;
  u16* WOtlo = p; p += 1024 * 1024;
  u16* Qb = p;    p += 4194304;
  u16* Kb = p;    p += 4194304;
  u16* Vtb = p;   p += 4194304;
  u16* AOhi = p;  p += 4194304;
  u16* AOlo = p;  p += 4194304;
  float* Csum = (float*)p;  // 2048 floats

  split_f32<<<4096, 256, 0, stream>>>(x, Xhi, Xlo, 1048576);
  prep_w<<<dim3(16, 48), 256, 0, stream>>>(krn, Wthi, Wtlo);
  prep_wo<<<dim3(16, 16), 256, 0, stream>>>(wo, WOthi, WOtlo);
  gemm_split<0><<<dim3(32, 24), 256, 0, stream>>>(Xhi, Xlo, Wthi, Wtlo, Qb, Kb,
                                                  Vtb, nullptr);
  colsum_v<<<32, 256, 0, stream>>>(Vtb, Csum);
  attn<<<512, 256, 0, stream>>>(Qb, Kb, Vtb, Csum, AOhi, AOlo);
  gemm_split<1><<<dim3(32, 8), 256, 0, stream>>>(AOhi, AOlo, WOthi, WOtlo,
                                                 nullptr, nullptr, nullptr, out);
}